// Round 5
// baseline (230.382 us; speedup 1.0000x reference)
//
#include <hip/hip_runtime.h>
#include <math.h>

#define N 8192
#define D 128
#define MARGIN 0.2f
#define PD_EPS 1e-6f

#define NLAB 16
#define NSUB 32
#define NBUK (NLAB + NSUB)           // 48 buckets total (16 label + 32 subject)
#define MAXPADL (N + NLAB * 64)      // 9216 padded label-sorted rows
#define MAXPADS (N + NSUB * 64)      // 10240 padded subject-sorted rows
#define MAXWL 144                    // sum ceil(cntL/64) <= 128+16
#define MAXWS 160                    // sum ceil(cntS/64) <= 128+32
#define MAXW  (MAXWL + MAXWS)        // 304 mining waves
#define MINEBLOCKS ((MAXW + 3) / 4)  // 76 blocks x 4 waves

#define HBLK 128                     // k_prep blocks (all co-resident: 128 < 256 CUs)
#define RPB  (N / HBLK)              // 64 rows per prep block
#define FBLK 64                      // k_finred blocks (64-long ticket chain ~ 3 us)
#define RPF  (N / FBLK)              // 128 rows per finred block

typedef __attribute__((ext_vector_type(8))) short bf16x8;  // 8 bf16 = 4 VGPRs
typedef __attribute__((ext_vector_type(4))) float f32x4;

__device__ __forceinline__ unsigned short f2bf(float f) {
    unsigned u = __float_as_uint(f);
    u += 0x7FFFu + ((u >> 16) & 1u);   // round-to-nearest-even
    return (unsigned short)(u >> 16);
}
__device__ __forceinline__ unsigned umn(unsigned a, unsigned b) { return a < b ? a : b; }

// ---------------- kernel 1: hist + bases + scatter + normalize (fused) -------
// 128 blocks, 64 rows each. Phases:
//  A: block-local LDS histogram -> plain-store histG[bucket][block]
//  B: LAST-arriving block (wrap-around atomicInc ticket, self-re-arming) scans
//     histG into per-(bucket,block) offsets, computes padded bases pbG, builds
//     the mining wave tables, pad-inits only the real pad slots, releases flag.
//  C: every block scatters its own 64 rows (LDS rank + block offset).
//  D: every block normalizes its own 64 rows straight into both bucketed bf16
//     arrays (slots kept in LDS — no global pos arrays, no extra kernel).
// Spin is safe: 128 blocks of 256 thr / ~1KB LDS are all co-resident.
__global__ __launch_bounds__(256) void k_prep(const float* __restrict__ z,
                                              const int* __restrict__ labels,
                                              const int* __restrict__ subjects,
                                              unsigned short* __restrict__ znbL,
                                              unsigned short* __restrict__ znbS,
                                              float* __restrict__ invn,
                                              int* __restrict__ metaL, int* __restrict__ permL,
                                              int* __restrict__ metaS, int* __restrict__ permS,
                                              int* __restrict__ histG, int* __restrict__ offG,
                                              int* __restrict__ pbG,
                                              int* __restrict__ wvA, int* __restrict__ wvJ,
                                              int* __restrict__ wvT,
                                              unsigned* __restrict__ tick) {
    __shared__ int h[NBUK], cur[NBUK], sL[RPB], sS[RPB];
    __shared__ int cnt48[NBUK], pbl[NBUK];
    __shared__ int amLast;
    const int t   = threadIdx.x;
    const int blk = blockIdx.x;
    const int r0  = blk * RPB;

    // ---- phase A: local histogram ----
    if (t < NBUK) h[t] = 0;
    __syncthreads();
    if (t < RPB) {
        atomicAdd(&h[labels[r0 + t]], 1);
        atomicAdd(&h[NLAB + subjects[r0 + t]], 1);
    }
    __syncthreads();
    if (t < NBUK) histG[t * HBLK + blk] = h[t];
    __threadfence();
    if (t == 0) amLast = (atomicInc(tick + 0, HBLK - 1) == HBLK - 1);  // wraps to 0
    __syncthreads();

    // ---- phase B: last block computes global layout ----
    if (amLast) {
        __threadfence();   // acquire all blocks' histG
        if (t < NBUK) {    // per-bucket scan over blocks
            int run = 0;
            for (int b = 0; b < HBLK; ++b) {
                int c = histG[t * HBLK + b];
                offG[t * HBLK + b] = run;
                run += c;
            }
            cnt48[t] = run;
        }
        __syncthreads();
        if (t == 0) {      // padded bases + wave tables (serial but tiny)
            int a = 0;
            for (int b = 0; b < NLAB; ++b) { pbl[b] = a; a += (cnt48[b] + 63) & ~63; }
            a = 0;
            for (int b = 0; b < NSUB; ++b) { pbl[NLAB + b] = a; a += (cnt48[NLAB + b] + 63) & ~63; }
            int w = 0;
            for (int b = 0; b < NLAB; ++b) {
                int nt = (cnt48[b] + 63) >> 6, base = pbl[b];
                for (int q = 0; q < nt; ++q) { wvA[w] = base + q * 64; wvJ[w] = base; wvT[w] = nt; ++w; }
            }
            for (; w < MAXWL; ++w) { wvA[w] = 0; wvJ[w] = 0; wvT[w] = 0; }
            for (int b = 0; b < NSUB; ++b) {
                int nt = (cnt48[NLAB + b] + 63) >> 6, base = pbl[NLAB + b];
                for (int q = 0; q < nt; ++q) { wvA[w] = base + q * 64; wvJ[w] = base; wvT[w] = nt; ++w; }
            }
            for (; w < MAXW; ++w) { wvA[w] = 0; wvJ[w] = 0; wvT[w] = 0; }
        }
        __syncthreads();
        if (t < NBUK) {
            pbG[t] = pbl[t];
            // pad-init only real pad slots (<= 63 per bucket)
            int cnt = cnt48[t], base = pbl[t], padded = (cnt + 63) & ~63;
            if (t < NLAB) {
                for (int k = cnt; k < padded; ++k) { metaL[base + k] = 1024; permL[base + k] = N; }
            } else {
                for (int k = cnt; k < padded; ++k) { metaS[base + k] = 1024; permS[base + k] = N; }
            }
        }
        __threadfence();
        if (t == 0) __hip_atomic_store(tick + 1, 1u, __ATOMIC_RELEASE, __HIP_MEMORY_SCOPE_AGENT);
    }

    // ---- spin until layout published (all threads; wave-broadcast load) ----
    while (__hip_atomic_load(tick + 1, __ATOMIC_ACQUIRE, __HIP_MEMORY_SCOPE_AGENT) == 0u)
        __builtin_amdgcn_s_sleep(8);
    __syncthreads();

    // ---- phase C: scatter this block's 64 rows ----
    if (t < NBUK) cur[t] = 0;
    __syncthreads();
    if (t < RPB) {
        int row = r0 + t;
        int lab = labels[row], sub = subjects[row];
        int me = lab * 32 + sub;
        int rl = atomicAdd(&cur[lab], 1);
        int slotL = pbG[lab] + offG[lab * HBLK + blk] + rl;
        metaL[slotL] = me; permL[slotL] = row; sL[t] = slotL;
        int rs = atomicAdd(&cur[NLAB + sub], 1);
        int slotS = pbG[NLAB + sub] + offG[(NLAB + sub) * HBLK + blk] + rs;
        metaS[slotS] = me; permS[slotS] = row; sS[t] = slotS;
    }
    __syncthreads();

    // ---- phase D: normalize this block's rows into both bucketed arrays ----
    const int wv = t >> 6, lane = t & 63;
    for (int rr = 0; rr < RPB / 4; ++rr) {        // 16 rows per wave
        int idx = wv * (RPB / 4) + rr;
        int row = r0 + idx;
        float2 v = ((const float2*)(z + (size_t)row * D))[lane];
        float ss = v.x * v.x + v.y * v.y;
        #pragma unroll
        for (int m = 1; m < 64; m <<= 1) ss += __shfl_xor(ss, m, 64);
        float norm = fmaxf(sqrtf(ss), 1e-12f);
        ushort2 b; b.x = f2bf(v.x / norm); b.y = f2bf(v.y / norm);
        int kl = sL[idx], ks = sS[idx];
        ((ushort2*)(znbL + (size_t)kl * D))[lane] = b;
        ((ushort2*)(znbS + (size_t)ks * D))[lane] = b;
        if (lane == 0) invn[row] = 1.0f / norm;
    }

    // ---- re-arm the release flag for the next launch (last finisher) ----
    __threadfence();
    if (t == 0) {
        if (atomicInc(tick + 2, HBLK - 1) == HBLK - 1)
            __hip_atomic_store(tick + 1, 0u, __ATOMIC_RELEASE, __HIP_MEMORY_SCOPE_AGENT);
    }
}

// ---------------- kernel 2: bucketed MFMA mining (unchanged from r4) ---------
// Wave w < MAXWL: pos-mining inside one label bucket (x=(mi^mj) in [1,31]).
// Wave w >= MAXWL: neg-mining inside one subject bucket (x in {32,...,480};
// subject bits cancel in-bucket so x<32 cannot occur). Pads carry meta=1024 so
// (x-1u)<thr also excludes them and the diagonal. Keys XOR'd with `inv` so one
// min-reduce serves min (pos) and max (neg).
__global__ __launch_bounds__(256) void k_mine(const unsigned short* __restrict__ znbL,
                                              const unsigned short* __restrict__ znbS,
                                              const int* __restrict__ metaL, const int* __restrict__ permL,
                                              const int* __restrict__ metaS, const int* __restrict__ permS,
                                              const int* __restrict__ wvA, const int* __restrict__ wvJ,
                                              const int* __restrict__ wvT,
                                              unsigned* __restrict__ posk, unsigned* __restrict__ negk) {
    const int wave = threadIdx.x >> 6;
    const int lane = threadIdx.x & 63;
    const int w    = blockIdx.x * 4 + wave;
    const int nt   = wvT[w];
    if (nt == 0) return;                          // unused slot (wave-uniform)
    const bool isPos = (w < MAXWL);
    const unsigned short* zb = isPos ? znbL : znbS;
    const int* mt = isPos ? metaL : metaS;
    const int* pm = isPos ? permL : permS;
    const unsigned thr = isPos ? 31u : 1023u;
    const unsigned inv = isPos ? 0u : 0xFFFFFFFFu;
    const int ab = wvA[w];
    const int jb = wvJ[w];
    const int m    = lane & 15;
    const int quad = lane >> 4;

    bf16x8 afrag[4][4];
    #pragma unroll
    for (int u = 0; u < 4; ++u)
        #pragma unroll
        for (int s = 0; s < 4; ++s)
            afrag[u][s] = *(const bf16x8*)(zb + (size_t)(ab + u * 16 + m) * D + s * 32 + quad * 8);

    int mi[16];
    #pragma unroll
    for (int u = 0; u < 4; ++u)
        #pragma unroll
        for (int r = 0; r < 4; ++r)
            mi[u * 4 + r] = mt[ab + u * 16 + quad * 4 + r];

    unsigned best[16];
    #pragma unroll
    for (int s = 0; s < 16; ++s) best[s] = 0xFFFFFFFFu;

    for (int t = 0; t < nt; ++t) {
        const int jt = jb + t * 64;
        int mjv[4], jov[4];
        #pragma unroll
        for (int v = 0; v < 4; ++v) {
            int jr = jt + v * 16 + m;
            mjv[v] = mt[jr];
            jov[v] = pm[jr];
        }

        f32x4 acc[4][4];
        #pragma unroll
        for (int u = 0; u < 4; ++u)
            #pragma unroll
            for (int v = 0; v < 4; ++v)
                acc[u][v] = (f32x4){0.f, 0.f, 0.f, 0.f};

        #pragma unroll
        for (int s = 0; s < 4; ++s) {
            bf16x8 bf[4];
            #pragma unroll
            for (int v = 0; v < 4; ++v)
                bf[v] = *(const bf16x8*)(zb + (size_t)(jt + v * 16 + m) * D + s * 32 + quad * 8);
            #pragma unroll
            for (int u = 0; u < 4; ++u)
                #pragma unroll
                for (int v = 0; v < 4; ++v)
                    acc[u][v] = __builtin_amdgcn_mfma_f32_16x16x32_bf16(afrag[u][s], bf[v], acc[u][v], 0, 0, 0);
        }

        #pragma unroll
        for (int v = 0; v < 4; ++v) {
            #pragma unroll
            for (int u = 0; u < 4; ++u)
                #pragma unroll
                for (int r = 0; r < 4; ++r) {
                    float dot = acc[u][v][r];
                    unsigned key = (((__float_as_uint(dot + 2.0f)) & 0xFFFFE000u) | (unsigned)jov[v]) ^ inv;
                    unsigned x = (unsigned)(mi[u * 4 + r] ^ mjv[v]);
                    bool c = (x - 1u) < thr;
                    best[u * 4 + r] = umn(best[u * 4 + r], c ? key : 0xFFFFFFFFu);
                }
        }
    }

    #pragma unroll
    for (int mm = 1; mm < 16; mm <<= 1)
        #pragma unroll
        for (int s = 0; s < 16; ++s)
            best[s] = umn(best[s], (unsigned)__shfl_xor((int)best[s], mm, 64));

    if (m == 0) {
        unsigned* dst = isPos ? posk : negk;
        #pragma unroll
        for (int u = 0; u < 4; ++u)
            #pragma unroll
            for (int r = 0; r < 4; ++r) {
                int orig = pm[ab + u * 16 + quad * 4 + r];
                if (orig < N) dst[orig] = best[u * 4 + r] ^ inv;
            }
    }
}

// ---------------- kernel 3: hinge + last-block deterministic reduce ----------
// 64 blocks x 4 waves x 32 rows. per/vld materialized exactly as r4's k_final;
// last-arriving block (64-long ticket, self-resetting) runs r4's k_reduce body
// verbatim -> bit-identical output to the passing r4 kernel.
__global__ __launch_bounds__(256) void k_finred(const float* __restrict__ z,
                                                const float* __restrict__ invn,
                                                const unsigned* __restrict__ posk,
                                                const unsigned* __restrict__ negk,
                                                float* __restrict__ per, float* __restrict__ vld,
                                                unsigned* __restrict__ tick,
                                                float* __restrict__ out) {
    __shared__ float s1[256], s2[256];
    __shared__ int amLast;
    const int t  = threadIdx.x;
    const int wv = t >> 6, lane = t & 63;
    const int base = blockIdx.x * RPF + wv * (RPF / 4);

    #pragma unroll 2
    for (int rr = 0; rr < RPF / 4; ++rr) {
        int row = base + rr;
        unsigned mp = posk[row];
        unsigned mn = negk[row];
        bool valid = (mp != 0xFFFFFFFFu) && (mn != 0u);
        int pi = valid ? (int)(mp & 8191u) : 0;
        int ni = valid ? (int)(mn & 8191u) : 0;
        float ia = invn[row], ip = invn[pi], iq = invn[ni];
        float2 a = ((const float2*)(z + (size_t)row * D))[lane];
        float2 p = ((const float2*)(z + (size_t)pi  * D))[lane];
        float2 q = ((const float2*)(z + (size_t)ni  * D))[lane];
        float dx = a.x * ia - p.x * ip + PD_EPS, dy = a.y * ia - p.y * ip + PD_EPS;
        float sap = dx * dx + dy * dy;
        dx = a.x * ia - q.x * iq + PD_EPS; dy = a.y * ia - q.y * iq + PD_EPS;
        float san = dx * dx + dy * dy;
        #pragma unroll
        for (int m = 1; m < 64; m <<= 1) {
            sap += __shfl_xor(sap, m, 64);
            san += __shfl_xor(san, m, 64);
        }
        if (lane == 0) {
            float l = fmaxf(sqrtf(sap) - sqrtf(san) + MARGIN, 0.0f);
            per[row] = valid ? l : 0.0f;
            vld[row] = valid ? 1.0f : 0.0f;
        }
    }

    __threadfence();
    __syncthreads();
    if (t == 0) amLast = (atomicInc(tick + 3, FBLK - 1) == FBLK - 1);  // wraps to 0
    __syncthreads();
    if (amLast) {
        __threadfence();   // acquire all blocks' per/vld
        float a = 0.f, b = 0.f;
        for (int i = t; i < N; i += 256) { a += per[i]; b += vld[i]; }
        s1[t] = a; s2[t] = b;
        __syncthreads();
        for (int w = 128; w > 0; w >>= 1) {
            if (t < w) { s1[t] += s1[t + w]; s2[t] += s2[t + w]; }
            __syncthreads();
        }
        if (t == 0) {
            float cnt = s2[0];
            out[0] = (cnt > 0.f) ? s1[0] / fmaxf(cnt, 1.f) : 0.f;
        }
    }
}

extern "C" void kernel_launch(void* const* d_in, const int* in_sizes, int n_in,
                              void* d_out, int out_size, void* d_ws, size_t ws_size,
                              hipStream_t stream) {
    const float* z        = (const float*)d_in[0];
    const int*   labels   = (const int*)d_in[1];
    const int*   subjects = (const int*)d_in[2];
    float* out = (float*)d_out;

    char* ws = (char*)d_ws;
    size_t o = 0;
    unsigned short* znbL = (unsigned short*)(ws + o); o += (size_t)MAXPADL * D * 2;  // 2,359,296
    unsigned short* znbS = (unsigned short*)(ws + o); o += (size_t)MAXPADS * D * 2;  // 2,621,440
    float* invn  = (float*)(ws + o); o += N * 4;
    int* metaL = (int*)(ws + o); o += MAXPADL * 4;
    int* permL = (int*)(ws + o); o += MAXPADL * 4;
    int* metaS = (int*)(ws + o); o += MAXPADS * 4;
    int* permS = (int*)(ws + o); o += MAXPADS * 4;
    int* histG = (int*)(ws + o); o += NBUK * HBLK * 4;   // 24 KB
    int* offG  = (int*)(ws + o); o += NBUK * HBLK * 4;   // 24 KB
    int* pbG   = (int*)(ws + o); o += 256;
    int* wvA   = (int*)(ws + o); o += 2048;
    int* wvJ   = (int*)(ws + o); o += 2048;
    int* wvT   = (int*)(ws + o); o += 2048;
    unsigned* posk = (unsigned*)(ws + o); o += N * 4;
    unsigned* negk = (unsigned*)(ws + o); o += N * 4;
    float* per = (float*)(ws + o); o += N * 4;
    float* vld = (float*)(ws + o); o += N * 4;
    unsigned* tick = (unsigned*)(ws + o); o += 64;        // total ~5.5 MB

    // belt-and-suspenders: tickets also self-reset via wrap-around atomicInc
    hipMemsetAsync(tick, 0, 64, stream);

    k_prep<<<dim3(HBLK), dim3(256), 0, stream>>>(z, labels, subjects, znbL, znbS, invn,
                                                 metaL, permL, metaS, permS,
                                                 histG, offG, pbG, wvA, wvJ, wvT, tick);
    k_mine<<<dim3(MINEBLOCKS), dim3(256), 0, stream>>>(znbL, znbS, metaL, permL, metaS, permS,
                                                       wvA, wvJ, wvT, posk, negk);
    k_finred<<<dim3(FBLK), dim3(256), 0, stream>>>(z, invn, posk, negk, per, vld, tick, out);
}